// Round 1
// baseline (522.815 us; speedup 1.0000x reference)
//
#include <hip/hip_runtime.h>
#include <hip/hip_bf16.h>
#include <math.h>

// Problem constants
#define VV 50257
#define EE 1024
#define HH 1024
#define SS 2048
#define VS (VV + SS)   // 52305

// Workspace layout (float offsets)
#define OFF_LOGA   0          // attn logits [2048]
#define OFF_ATTW   2048       // softmaxed attn weights [2048]
#define OFF_RHO    4096       // normalized rho [2048]
#define OFF_CTX    6144       // ctx accumulator [2048]  (memset 0)
#define OFF_SEL    8192       // selective ctx accumulator [2048]  (memset 0)
#define OFF_LSTMIN 10240      // lstm_in [3072] = [xe, selective, attentive]
#define OFF_GATES  13312      // gates [4096]
#define OFF_H1     17408      // h1 [1024]
#define OFF_LOG    18432      // score logits [52305]
#define OFF_MS     70784      // softmax block maxes [128]
#define OFF_LS     70912      // softmax block sums [128]
#define OFF_G      71040      // [0]=global max, [1]=1/total
#define OFF_TT     71168      // Ttanh [2048*1024] fp32 (16B aligned)

typedef __attribute__((ext_vector_type(8))) short bf16x8;
typedef __attribute__((ext_vector_type(4))) float f32x4;

__device__ inline float wave_reduce(float v) {
    #pragma unroll
    for (int off = 32; off > 0; off >>= 1) v += __shfl_down(v, off, 64);
    return v;
}

__device__ inline unsigned short f2bf(float f) {
    unsigned int u = __builtin_bit_cast(unsigned int, f);
    u += 0x7FFFu + ((u >> 16) & 1u);
    return (unsigned short)(u >> 16);
}

// ---- A: attn logits[s] = dot(concat(x,h0), attn_W[s]) + attn_b[s], one wave/row
__global__ void k_attn_logits(const float* __restrict__ x, const float* __restrict__ h0,
                              const float* __restrict__ attn_W, const float* __restrict__ attn_b,
                              float* __restrict__ out) {
    int wave = (blockIdx.x * blockDim.x + threadIdx.x) >> 6;
    int lane = threadIdx.x & 63;
    if (wave >= SS) return;
    const float4* rp = (const float4*)(attn_W + (size_t)wave * 2048);
    float acc = 0.f;
    #pragma unroll
    for (int k = 0; k < 8; ++k) {
        int idx = lane + 64 * k;
        float4 w = rp[idx];
        int j = idx * 4;
        const float* cat = (j < 1024) ? (x + j) : (h0 + (j - 1024));
        acc += w.x * cat[0] + w.y * cat[1] + w.z * cat[2] + w.w * cat[3];
    }
    acc = wave_reduce(acc);
    if (lane == 0) out[wave] = acc + attn_b[wave];
}

// ---- B: softmax over 2048 logits, rho (normalized), copy xe into lstm_in
__global__ void k_prep(const float* __restrict__ logits, const int* __restrict__ sentence,
                       const float* __restrict__ prev_probs, const int* __restrict__ prev_word,
                       const float* __restrict__ x,
                       float* __restrict__ attn_w, float* __restrict__ rho,
                       float* __restrict__ lstm_in) {
    __shared__ float red[256];
    int tid = threadIdx.x;
    float m = -1e30f;
    for (int s = tid; s < SS; s += 256) m = fmaxf(m, logits[s]);
    red[tid] = m; __syncthreads();
    for (int o = 128; o > 0; o >>= 1) { if (tid < o) red[tid] = fmaxf(red[tid], red[tid + o]); __syncthreads(); }
    m = red[0]; __syncthreads();
    float sum = 0.f;
    for (int s = tid; s < SS; s += 256) sum += expf(logits[s] - m);
    red[tid] = sum; __syncthreads();
    for (int o = 128; o > 0; o >>= 1) { if (tid < o) red[tid] += red[tid + o]; __syncthreads(); }
    float inv = 1.f / red[0]; __syncthreads();
    for (int s = tid; s < SS; s += 256) attn_w[s] = expf(logits[s] - m) * inv;
    // rho
    int pw = prev_word[0];
    float rsum = 0.f;
    for (int s = tid; s < SS; s += 256) rsum += (sentence[s] == pw) ? prev_probs[VV + s] : 0.f;
    red[tid] = rsum; __syncthreads();
    for (int o = 128; o > 0; o >>= 1) { if (tid < o) red[tid] += red[tid + o]; __syncthreads(); }
    float rinv = 1.f / (red[0] + 1e-9f); __syncthreads();
    for (int s = tid; s < SS; s += 256) rho[s] = ((sentence[s] == pw) ? prev_probs[VV + s] : 0.f) * rinv;
    // xe copy
    for (int j = tid; j < EE; j += 256) lstm_in[j] = x[j];
}

// ---- C: ctx[col] = sum_s attn_w[s]*enc[s][col]; selctx likewise with rho. grid (8, 32)
__global__ void k_ctx(const float* __restrict__ enc, const float* __restrict__ attn_w,
                      const float* __restrict__ rho, float* __restrict__ ctx,
                      float* __restrict__ selctx) {
    int col = blockIdx.x * 256 + threadIdx.x;
    int s0 = blockIdx.y * 64;
    float a = 0.f, r = 0.f;
    const float* p = enc + (size_t)s0 * 2048 + col;
    #pragma unroll 4
    for (int i = 0; i < 64; ++i) {
        float v = p[(size_t)i * 2048];
        a += attn_w[s0 + i] * v;
        r += rho[s0 + i] * v;
    }
    atomicAdd(&ctx[col], a);
    atomicAdd(&selctx[col], r);
}

// ---- D: attentive (comb_W) + selective (Ws_W) matvecs -> lstm_in, one wave/row
__global__ void k_comb(const float* __restrict__ ctx, const float* __restrict__ selctx,
                       const float* __restrict__ comb_W, const float* __restrict__ comb_b,
                       const float* __restrict__ Ws_W, const float* __restrict__ Ws_b,
                       float* __restrict__ lstm_in) {
    int wave = (blockIdx.x * blockDim.x + threadIdx.x) >> 6;
    int lane = threadIdx.x & 63;
    if (wave >= 2048) return;
    bool sel = wave >= 1024;
    int i = sel ? wave - 1024 : wave;
    const float4* rp = (const float4*)((sel ? Ws_W : comb_W) + (size_t)i * 2048);
    const float4* vp = (const float4*)(sel ? selctx : ctx);
    float acc = 0.f;
    #pragma unroll
    for (int k = 0; k < 8; ++k) {
        int idx = lane + 64 * k;
        float4 w = rp[idx]; float4 v = vp[idx];
        acc += w.x * v.x + w.y * v.y + w.z * v.z + w.w * v.w;
    }
    acc = wave_reduce(acc);
    if (lane == 0) lstm_in[sel ? (1024 + i) : (2048 + i)] = acc + (sel ? Ws_b[i] : comb_b[i]);
}

// ---- E: gates[r] = lstm_in.W_ih[r] + h0.W_hh[r] + b_ih[r] + b_hh[r], one wave/row
__global__ void k_gates(const float* __restrict__ lstm_in, const float* __restrict__ h0,
                        const float* __restrict__ W_ih, const float* __restrict__ W_hh,
                        const float* __restrict__ b_ih, const float* __restrict__ b_hh,
                        float* __restrict__ gates) {
    int wave = (blockIdx.x * blockDim.x + threadIdx.x) >> 6;
    int lane = threadIdx.x & 63;
    if (wave >= 4096) return;
    const float4* rp = (const float4*)(W_ih + (size_t)wave * 3072);
    const float4* vp = (const float4*)lstm_in;
    float acc = 0.f;
    #pragma unroll
    for (int k = 0; k < 12; ++k) {
        int idx = lane + 64 * k;
        float4 w = rp[idx]; float4 v = vp[idx];
        acc += w.x * v.x + w.y * v.y + w.z * v.z + w.w * v.w;
    }
    const float4* hp = (const float4*)(W_hh + (size_t)wave * 1024);
    const float4* h4 = (const float4*)h0;
    #pragma unroll
    for (int k = 0; k < 4; ++k) {
        int idx = lane + 64 * k;
        float4 w = hp[idx]; float4 v = h4[idx];
        acc += w.x * v.x + w.y * v.y + w.z * v.z + w.w * v.w;
    }
    acc = wave_reduce(acc);
    if (lane == 0) gates[wave] = acc + b_ih[wave] + b_hh[wave];
}

// ---- F: LSTM pointwise -> h1, c1 into d_out (+ h1 copy in ws)
__global__ void k_lstm(const float* __restrict__ gates, const float* __restrict__ c0,
                       float* __restrict__ out, float* __restrict__ h1ws) {
    int k = blockIdx.x * 256 + threadIdx.x;  // grid 4 -> 1024
    float ig = gates[k], fg = gates[1024 + k], gg = gates[2048 + k], og = gates[3072 + k];
    float si = 1.f / (1.f + expf(-ig));
    float sf = 1.f / (1.f + expf(-fg));
    float so = 1.f / (1.f + expf(-og));
    float c1 = sf * c0[k] + si * tanhf(gg);
    float h1 = so * tanhf(c1);
    out[VS + k] = h1;
    out[VS + 1024 + k] = c1;
    h1ws[k] = h1;
}

// ---- T: Ttanh = tanh(enc @ Wc_W^T + Wc_b), bf16 MFMA, 128x128 tile, grid (8,16)
__global__ __launch_bounds__(256) void k_wc_gemm(const float* __restrict__ A,   // enc 2048x2048
                                                 const float* __restrict__ B,   // Wc_W 1024x2048
                                                 const float* __restrict__ bias,
                                                 float* __restrict__ C) {       // 2048x1024
    __shared__ unsigned short As[128 * 32];
    __shared__ unsigned short Bs[128 * 32];
    int tid = threadIdx.x;
    int mbase = blockIdx.y * 128;
    int nbase = blockIdx.x * 128;
    int lane = tid & 63;
    int wid = tid >> 6;
    int wm = (wid >> 1) * 64;
    int wn = (wid & 1) * 64;
    int lrow = lane & 15;
    int lk = (lane >> 4) * 8;
    f32x4 acc[4][4] = {};
    for (int k0 = 0; k0 < 2048; k0 += 32) {
        #pragma unroll
        for (int i = 0; i < 4; ++i) {
            int fi = tid + 256 * i;      // 0..1023
            int row = fi >> 3;
            int kg = fi & 7;
            float4 v = *(const float4*)(A + (size_t)(mbase + row) * 2048 + k0 + kg * 4);
            ushort4 a4 = { f2bf(v.x), f2bf(v.y), f2bf(v.z), f2bf(v.w) };
            *(ushort4*)(As + row * 32 + kg * 4) = a4;
            float4 w = *(const float4*)(B + (size_t)(nbase + row) * 2048 + k0 + kg * 4);
            ushort4 b4 = { f2bf(w.x), f2bf(w.y), f2bf(w.z), f2bf(w.w) };
            *(ushort4*)(Bs + row * 32 + kg * 4) = b4;
        }
        __syncthreads();
        bf16x8 af[4], bfr[4];
        #pragma unroll
        for (int t = 0; t < 4; ++t) {
            af[t]  = *(const bf16x8*)(As + (wm + t * 16 + lrow) * 32 + lk);
            bfr[t] = *(const bf16x8*)(Bs + (wn + t * 16 + lrow) * 32 + lk);
        }
        #pragma unroll
        for (int mt = 0; mt < 4; ++mt)
            #pragma unroll
            for (int nt = 0; nt < 4; ++nt)
                acc[mt][nt] = __builtin_amdgcn_mfma_f32_16x16x32_bf16(af[mt], bfr[nt], acc[mt][nt], 0, 0, 0);
        __syncthreads();
    }
    int crow0 = (lane >> 4) * 4;
    int ccol = lane & 15;
    #pragma unroll
    for (int mt = 0; mt < 4; ++mt)
        #pragma unroll
        for (int nt = 0; nt < 4; ++nt) {
            int col = nbase + wn + nt * 16 + ccol;
            float bb = bias[col];
            #pragma unroll
            for (int r = 0; r < 4; ++r) {
                int row = mbase + wm + mt * 16 + crow0 + r;
                C[(size_t)row * 1024 + col] = tanhf(acc[mt][nt][r] + bb);
            }
        }
}

// ---- G: logits[v] = dot(h1, Wo_W[v]) + Wo_b[v]  (v<V)  or  dot(h1, Ttanh[v-V])
__global__ void k_scores(const float* __restrict__ Wo_W, const float* __restrict__ Wo_b,
                         const float* __restrict__ Tt, const float* __restrict__ h1,
                         float* __restrict__ logits) {
    int wave = (blockIdx.x * blockDim.x + threadIdx.x) >> 6;
    int lane = threadIdx.x & 63;
    if (wave >= VS) return;
    const float* row = (wave < VV) ? (Wo_W + (size_t)wave * 1024) : (Tt + (size_t)(wave - VV) * 1024);
    const float4* rp = (const float4*)row;
    const float4* hp = (const float4*)h1;
    float acc = 0.f;
    #pragma unroll
    for (int k = 0; k < 4; ++k) {
        int idx = lane + 64 * k;
        float4 w = rp[idx]; float4 v = hp[idx];
        acc += w.x * v.x + w.y * v.y + w.z * v.z + w.w * v.w;
    }
    acc = wave_reduce(acc);
    if (lane == 0) logits[wave] = acc + (wave < VV ? Wo_b[wave] : 0.f);
}

// ---- softmax over 52305: S1 per-block online (m,l), S2 merge, S3 write
__global__ void k_sm1(const float* __restrict__ logits, float* __restrict__ ms, float* __restrict__ ls) {
    __shared__ float rm[256], rl[256];
    int tid = threadIdx.x;
    float m = -1e30f, l = 0.f;
    for (int v = blockIdx.x * 256 + tid; v < VS; v += 128 * 256) {
        float x = logits[v];
        float nm = fmaxf(m, x);
        l = l * expf(m - nm) + expf(x - nm);
        m = nm;
    }
    rm[tid] = m; rl[tid] = l; __syncthreads();
    for (int o = 128; o > 0; o >>= 1) {
        if (tid < o) {
            float m2 = rm[tid + o], l2 = rl[tid + o];
            float nm = fmaxf(rm[tid], m2);
            rl[tid] = rl[tid] * expf(rm[tid] - nm) + l2 * expf(m2 - nm);
            rm[tid] = nm;
        }
        __syncthreads();
    }
    if (tid == 0) { ms[blockIdx.x] = rm[0]; ls[blockIdx.x] = rl[0]; }
}

__global__ void k_sm2(const float* __restrict__ ms, const float* __restrict__ ls, float* __restrict__ g) {
    __shared__ float rm[128], rl[128];
    int tid = threadIdx.x;  // 128 threads
    rm[tid] = ms[tid]; rl[tid] = ls[tid]; __syncthreads();
    for (int o = 64; o > 0; o >>= 1) {
        if (tid < o) {
            float m2 = rm[tid + o], l2 = rl[tid + o];
            float nm = fmaxf(rm[tid], m2);
            rl[tid] = rl[tid] * expf(rm[tid] - nm) + l2 * expf(m2 - nm);
            rm[tid] = nm;
        }
        __syncthreads();
    }
    if (tid == 0) { g[0] = rm[0]; g[1] = 1.f / rl[0]; }
}

__global__ void k_sm3(const float* __restrict__ logits, const float* __restrict__ g,
                      float* __restrict__ out) {
    int v = blockIdx.x * 256 + threadIdx.x;
    if (v < VS) out[v] = expf(logits[v] - g[0]) * g[1];
}

extern "C" void kernel_launch(void* const* d_in, const int* in_sizes, int n_in,
                              void* d_out, int out_size, void* d_ws, size_t ws_size,
                              hipStream_t stream) {
    (void)in_sizes; (void)n_in; (void)out_size; (void)ws_size;
    const float* x          = (const float*)d_in[0];
    const float* enc        = (const float*)d_in[1];
    const int*   sentence   = (const int*)d_in[2];
    const float* prev_probs = (const float*)d_in[3];
    const float* h0         = (const float*)d_in[4];
    const float* c0         = (const float*)d_in[5];
    const float* attn_W     = (const float*)d_in[6];
    const float* attn_b     = (const float*)d_in[7];
    const float* comb_W     = (const float*)d_in[8];
    const float* comb_b     = (const float*)d_in[9];
    const float* Ws_W       = (const float*)d_in[10];
    const float* Ws_b       = (const float*)d_in[11];
    const float* Wo_W       = (const float*)d_in[12];
    const float* Wo_b       = (const float*)d_in[13];
    const float* Wc_W       = (const float*)d_in[14];
    const float* Wc_b       = (const float*)d_in[15];
    const float* W_ih       = (const float*)d_in[16];
    const float* W_hh       = (const float*)d_in[17];
    const float* b_ih       = (const float*)d_in[18];
    const float* b_hh       = (const float*)d_in[19];
    const int*   prev_word  = (const int*)d_in[20];
    float* ws  = (float*)d_ws;
    float* out = (float*)d_out;

    hipMemsetAsync(ws + OFF_CTX, 0, 4096 * sizeof(float), stream);
    k_wc_gemm<<<dim3(8, 16), 256, 0, stream>>>(enc, Wc_W, Wc_b, ws + OFF_TT);
    k_attn_logits<<<512, 256, 0, stream>>>(x, h0, attn_W, attn_b, ws + OFF_LOGA);
    k_prep<<<1, 256, 0, stream>>>(ws + OFF_LOGA, sentence, prev_probs, prev_word, x,
                                  ws + OFF_ATTW, ws + OFF_RHO, ws + OFF_LSTMIN);
    k_ctx<<<dim3(8, 32), 256, 0, stream>>>(enc, ws + OFF_ATTW, ws + OFF_RHO,
                                           ws + OFF_CTX, ws + OFF_SEL);
    k_comb<<<512, 256, 0, stream>>>(ws + OFF_CTX, ws + OFF_SEL, comb_W, comb_b,
                                    Ws_W, Ws_b, ws + OFF_LSTMIN);
    k_gates<<<1024, 256, 0, stream>>>(ws + OFF_LSTMIN, h0, W_ih, W_hh, b_ih, b_hh,
                                      ws + OFF_GATES);
    k_lstm<<<4, 256, 0, stream>>>(ws + OFF_GATES, c0, out, ws + OFF_H1);
    k_scores<<<13077, 256, 0, stream>>>(Wo_W, Wo_b, ws + OFF_TT, ws + OFF_H1, ws + OFF_LOG);
    k_sm1<<<128, 256, 0, stream>>>(ws + OFF_LOG, ws + OFF_MS, ws + OFF_LS);
    k_sm2<<<1, 128, 0, stream>>>(ws + OFF_MS, ws + OFF_LS, ws + OFF_G);
    k_sm3<<<205, 256, 0, stream>>>(ws + OFF_LOG, ws + OFF_G, out);
}

// Round 2
// 480.456 us; speedup vs baseline: 1.0882x; 1.0882x over previous
//
#include <hip/hip_runtime.h>
#include <hip/hip_bf16.h>
#include <math.h>

// Problem constants
#define VV 50257
#define EE 1024
#define HH 1024
#define SS 2048
#define VS (VV + SS)   // 52305

// Workspace layout (float offsets)
#define OFF_LOGA   0          // attn logits [2048]
#define OFF_ATTW   2048       // softmaxed attn weights [2048]
#define OFF_RHO    4096       // normalized rho [2048]
#define OFF_CTX    6144       // ctx accumulator [2048]  (zeroed in k_prep)
#define OFF_SEL    8192       // selective ctx accumulator [2048] (zeroed in k_prep)
#define OFF_LSTMIN 10240      // lstm_in [3072] = [xe, selective, attentive]
#define OFF_GATES  13312      // gates [4096]
#define OFF_H1     17408      // h1 [1024]
#define OFF_LOG    18432      // score logits [52305]
#define OFF_MS     70784      // softmax block maxes [128]
#define OFF_LS     70912      // softmax block sums [128]
#define OFF_G      71040      // [0]=global max, [1]=1/total
#define OFF_T0     71168      // Wc GEMM partial, K-half 0: [2048*1024] fp32
#define OFF_T1     (71168 + 2048*1024)   // K-half 1 partial

typedef __attribute__((ext_vector_type(8))) short bf16x8;
typedef __attribute__((ext_vector_type(4))) float f32x4;

__device__ inline float wave_reduce(float v) {
    #pragma unroll
    for (int off = 32; off > 0; off >>= 1) v += __shfl_down(v, off, 64);
    return v;
}

__device__ inline unsigned short f2bf(float f) {
    unsigned int u = __builtin_bit_cast(unsigned int, f);
    u += 0x7FFFu + ((u >> 16) & 1u);
    return (unsigned short)(u >> 16);
}

// ---- A: attn logits[s] = dot(concat(x,h0), attn_W[s]) + attn_b[s], one wave/row
__global__ void k_attn_logits(const float* __restrict__ x, const float* __restrict__ h0,
                              const float* __restrict__ attn_W, const float* __restrict__ attn_b,
                              float* __restrict__ out) {
    int wave = (blockIdx.x * blockDim.x + threadIdx.x) >> 6;
    int lane = threadIdx.x & 63;
    if (wave >= SS) return;
    const float4* rp = (const float4*)(attn_W + (size_t)wave * 2048);
    float acc = 0.f;
    #pragma unroll
    for (int k = 0; k < 8; ++k) {
        int idx = lane + 64 * k;
        float4 w = rp[idx];
        int j = idx * 4;
        const float* cat = (j < 1024) ? (x + j) : (h0 + (j - 1024));
        acc += w.x * cat[0] + w.y * cat[1] + w.z * cat[2] + w.w * cat[3];
    }
    acc = wave_reduce(acc);
    if (lane == 0) out[wave] = acc + attn_b[wave];
}

// ---- B: softmax over 2048 logits, rho (normalized), copy xe, zero ctx/sel accumulators
__global__ void k_prep(const float* __restrict__ logits, const int* __restrict__ sentence,
                       const float* __restrict__ prev_probs, const int* __restrict__ prev_word,
                       const float* __restrict__ x,
                       float* __restrict__ attn_w, float* __restrict__ rho,
                       float* __restrict__ lstm_in, float* __restrict__ ctxsel) {
    __shared__ float red[256];
    int tid = threadIdx.x;
    // zero ctx+sel (4096 floats) for the next kernel's atomics
    for (int j = tid; j < 4096; j += 256) ctxsel[j] = 0.f;
    float m = -1e30f;
    for (int s = tid; s < SS; s += 256) m = fmaxf(m, logits[s]);
    red[tid] = m; __syncthreads();
    for (int o = 128; o > 0; o >>= 1) { if (tid < o) red[tid] = fmaxf(red[tid], red[tid + o]); __syncthreads(); }
    m = red[0]; __syncthreads();
    float sum = 0.f;
    for (int s = tid; s < SS; s += 256) sum += expf(logits[s] - m);
    red[tid] = sum; __syncthreads();
    for (int o = 128; o > 0; o >>= 1) { if (tid < o) red[tid] += red[tid + o]; __syncthreads(); }
    float inv = 1.f / red[0]; __syncthreads();
    for (int s = tid; s < SS; s += 256) attn_w[s] = expf(logits[s] - m) * inv;
    // rho
    int pw = prev_word[0];
    float rsum = 0.f;
    for (int s = tid; s < SS; s += 256) rsum += (sentence[s] == pw) ? prev_probs[VV + s] : 0.f;
    red[tid] = rsum; __syncthreads();
    for (int o = 128; o > 0; o >>= 1) { if (tid < o) red[tid] += red[tid + o]; __syncthreads(); }
    float rinv = 1.f / (red[0] + 1e-9f); __syncthreads();
    for (int s = tid; s < SS; s += 256) rho[s] = ((sentence[s] == pw) ? prev_probs[VV + s] : 0.f) * rinv;
    // xe copy
    for (int j = tid; j < EE; j += 256) lstm_in[j] = x[j];
}

// ---- C: ctx[c] = sum_s attn_w[s]*enc[s][c]; selctx with rho. float4, grid (2, 32)
__global__ void k_ctx(const float* __restrict__ enc, const float* __restrict__ attn_w,
                      const float* __restrict__ rho, float* __restrict__ ctx,
                      float* __restrict__ selctx) {
    int col4 = blockIdx.x * 256 + threadIdx.x;   // 0..511 (512 float4 cols)
    int s0 = blockIdx.y * 64;
    float4 a = {0.f, 0.f, 0.f, 0.f}, r = {0.f, 0.f, 0.f, 0.f};
    const float4* p = (const float4*)enc + (size_t)s0 * 512 + col4;
    #pragma unroll 4
    for (int i = 0; i < 64; ++i) {
        float4 v = p[(size_t)i * 512];
        float w = attn_w[s0 + i], q = rho[s0 + i];
        a.x += w * v.x; a.y += w * v.y; a.z += w * v.z; a.w += w * v.w;
        r.x += q * v.x; r.y += q * v.y; r.z += q * v.z; r.w += q * v.w;
    }
    int c = col4 * 4;
    atomicAdd(&ctx[c], a.x); atomicAdd(&ctx[c+1], a.y); atomicAdd(&ctx[c+2], a.z); atomicAdd(&ctx[c+3], a.w);
    atomicAdd(&selctx[c], r.x); atomicAdd(&selctx[c+1], r.y); atomicAdd(&selctx[c+2], r.z); atomicAdd(&selctx[c+3], r.w);
}

// ---- D: attentive (comb_W) + selective (Ws_W) matvecs -> lstm_in, one wave/row
__global__ void k_comb(const float* __restrict__ ctx, const float* __restrict__ selctx,
                       const float* __restrict__ comb_W, const float* __restrict__ comb_b,
                       const float* __restrict__ Ws_W, const float* __restrict__ Ws_b,
                       float* __restrict__ lstm_in) {
    int wave = (blockIdx.x * blockDim.x + threadIdx.x) >> 6;
    int lane = threadIdx.x & 63;
    if (wave >= 2048) return;
    bool sel = wave >= 1024;
    int i = sel ? wave - 1024 : wave;
    const float4* rp = (const float4*)((sel ? Ws_W : comb_W) + (size_t)i * 2048);
    const float4* vp = (const float4*)(sel ? selctx : ctx);
    float acc = 0.f;
    #pragma unroll
    for (int k = 0; k < 8; ++k) {
        int idx = lane + 64 * k;
        float4 w = rp[idx]; float4 v = vp[idx];
        acc += w.x * v.x + w.y * v.y + w.z * v.z + w.w * v.w;
    }
    acc = wave_reduce(acc);
    if (lane == 0) lstm_in[sel ? (1024 + i) : (2048 + i)] = acc + (sel ? Ws_b[i] : comb_b[i]);
}

// ---- E (fused): blocks 0..1023 = LSTM gate matvecs; blocks 1024..1279 = Wc GEMM split-K
// gates[r] = lstm_in.W_ih[r] + h0.W_hh[r] + b_ih + b_hh  (4096 rows, one wave/row)
// GEMM: T{s}[2048x1024] = enc[.,sK..] @ Wc_W[.,sK..]^T  (bf16 MFMA, 128x128 tile, split-K=2)
__global__ __launch_bounds__(256) void k_gates_gemm(
        const float* __restrict__ lstm_in, const float* __restrict__ h0,
        const float* __restrict__ W_ih, const float* __restrict__ W_hh,
        const float* __restrict__ b_ih, const float* __restrict__ b_hh,
        float* __restrict__ gates,
        const float* __restrict__ A,      // enc 2048x2048
        const float* __restrict__ B,      // Wc_W 1024x2048
        float* __restrict__ T0, float* __restrict__ T1) {
    __shared__ unsigned short As[128 * 32];
    __shared__ unsigned short Bs[128 * 32];
    int tid = threadIdx.x;
    if (blockIdx.x < 1024) {
        // ---- gates path
        int wave = (blockIdx.x * 256 + tid) >> 6;
        int lane = tid & 63;
        const float4* rp = (const float4*)(W_ih + (size_t)wave * 3072);
        const float4* vp = (const float4*)lstm_in;
        float acc = 0.f;
        #pragma unroll
        for (int k = 0; k < 12; ++k) {
            int idx = lane + 64 * k;
            float4 w = rp[idx]; float4 v = vp[idx];
            acc += w.x * v.x + w.y * v.y + w.z * v.z + w.w * v.w;
        }
        const float4* hp = (const float4*)(W_hh + (size_t)wave * 1024);
        const float4* h4 = (const float4*)h0;
        #pragma unroll
        for (int k = 0; k < 4; ++k) {
            int idx = lane + 64 * k;
            float4 w = hp[idx]; float4 v = h4[idx];
            acc += w.x * v.x + w.y * v.y + w.z * v.z + w.w * v.w;
        }
        acc = wave_reduce(acc);
        if (lane == 0) gates[wave] = acc + b_ih[wave] + b_hh[wave];
        return;
    }
    // ---- GEMM path
    int gg = blockIdx.x - 1024;          // 0..255
    int sK = gg >> 7;                    // split-K index 0/1
    int rem = gg & 127;
    int mbase = (rem >> 3) * 128;        // 16 m-blocks
    int nbase = (rem & 7) * 128;         // 8 n-blocks
    float* C = sK ? T1 : T0;
    int lane = tid & 63;
    int wid = tid >> 6;
    int wm = (wid >> 1) * 64;
    int wn = (wid & 1) * 64;
    int lrow = lane & 15;
    int lk = (lane >> 4) * 8;
    f32x4 acc[4][4] = {};
    int kbeg = sK * 1024;
    for (int k0 = kbeg; k0 < kbeg + 1024; k0 += 32) {
        #pragma unroll
        for (int i = 0; i < 4; ++i) {
            int fi = tid + 256 * i;      // 0..1023
            int row = fi >> 3;
            int kg = fi & 7;
            float4 v = *(const float4*)(A + (size_t)(mbase + row) * 2048 + k0 + kg * 4);
            ushort4 a4 = { f2bf(v.x), f2bf(v.y), f2bf(v.z), f2bf(v.w) };
            *(ushort4*)(As + row * 32 + kg * 4) = a4;
            float4 w = *(const float4*)(B + (size_t)(nbase + row) * 2048 + k0 + kg * 4);
            ushort4 b4 = { f2bf(w.x), f2bf(w.y), f2bf(w.z), f2bf(w.w) };
            *(ushort4*)(Bs + row * 32 + kg * 4) = b4;
        }
        __syncthreads();
        bf16x8 af[4], bfr[4];
        #pragma unroll
        for (int t = 0; t < 4; ++t) {
            af[t]  = *(const bf16x8*)(As + (wm + t * 16 + lrow) * 32 + lk);
            bfr[t] = *(const bf16x8*)(Bs + (wn + t * 16 + lrow) * 32 + lk);
        }
        #pragma unroll
        for (int mt = 0; mt < 4; ++mt)
            #pragma unroll
            for (int nt = 0; nt < 4; ++nt)
                acc[mt][nt] = __builtin_amdgcn_mfma_f32_16x16x32_bf16(af[mt], bfr[nt], acc[mt][nt], 0, 0, 0);
        __syncthreads();
    }
    int crow0 = (lane >> 4) * 4;
    int ccol = lane & 15;
    #pragma unroll
    for (int mt = 0; mt < 4; ++mt)
        #pragma unroll
        for (int nt = 0; nt < 4; ++nt) {
            int col = nbase + wn + nt * 16 + ccol;
            #pragma unroll
            for (int r = 0; r < 4; ++r) {
                int row = mbase + wm + mt * 16 + crow0 + r;
                C[(size_t)row * 1024 + col] = acc[mt][nt][r];
            }
        }
}

// ---- F: LSTM pointwise -> h1, c1 into d_out (+ h1 copy in ws)
__global__ void k_lstm(const float* __restrict__ gates, const float* __restrict__ c0,
                       float* __restrict__ out, float* __restrict__ h1ws) {
    int k = blockIdx.x * 256 + threadIdx.x;  // grid 4 -> 1024
    float ig = gates[k], fg = gates[1024 + k], gg = gates[2048 + k], og = gates[3072 + k];
    float si = 1.f / (1.f + expf(-ig));
    float sf = 1.f / (1.f + expf(-fg));
    float so = 1.f / (1.f + expf(-og));
    float c1 = sf * c0[k] + si * tanhf(gg);
    float h1 = so * tanhf(c1);
    out[VS + k] = h1;
    out[VS + 1024 + k] = c1;
    h1ws[k] = h1;
}

// ---- G: logits[v] = dot(h1, Wo_W[v]) + Wo_b[v]  (v<V)
//         or dot(h1, tanh(T0[v-V]+T1[v-V]+Wc_b))  (v>=V)
__global__ void k_scores(const float* __restrict__ Wo_W, const float* __restrict__ Wo_b,
                         const float* __restrict__ T0, const float* __restrict__ T1,
                         const float* __restrict__ Wc_b,
                         const float* __restrict__ h1, float* __restrict__ logits) {
    int wave = (blockIdx.x * blockDim.x + threadIdx.x) >> 6;
    int lane = threadIdx.x & 63;
    if (wave >= VS) return;
    const float4* hp = (const float4*)h1;
    float acc = 0.f;
    if (wave < VV) {
        const float4* rp = (const float4*)(Wo_W + (size_t)wave * 1024);
        #pragma unroll
        for (int k = 0; k < 4; ++k) {
            int idx = lane + 64 * k;
            float4 w = rp[idx]; float4 v = hp[idx];
            acc += w.x * v.x + w.y * v.y + w.z * v.z + w.w * v.w;
        }
        acc = wave_reduce(acc);
        if (lane == 0) logits[wave] = acc + Wo_b[wave];
    } else {
        int r = wave - VV;
        const float4* p0 = (const float4*)(T0 + (size_t)r * 1024);
        const float4* p1 = (const float4*)(T1 + (size_t)r * 1024);
        const float4* bp = (const float4*)Wc_b;
        #pragma unroll
        for (int k = 0; k < 4; ++k) {
            int idx = lane + 64 * k;
            float4 a0 = p0[idx]; float4 a1 = p1[idx]; float4 bb = bp[idx]; float4 v = hp[idx];
            acc += tanhf(a0.x + a1.x + bb.x) * v.x + tanhf(a0.y + a1.y + bb.y) * v.y
                 + tanhf(a0.z + a1.z + bb.z) * v.z + tanhf(a0.w + a1.w + bb.w) * v.w;
        }
        acc = wave_reduce(acc);
        if (lane == 0) logits[wave] = acc;
    }
}

// ---- softmax over 52305: S1 per-block online (m,l), S2 merge, S3 write
__global__ void k_sm1(const float* __restrict__ logits, float* __restrict__ ms, float* __restrict__ ls) {
    __shared__ float rm[256], rl[256];
    int tid = threadIdx.x;
    float m = -1e30f, l = 0.f;
    for (int v = blockIdx.x * 256 + tid; v < VS; v += 128 * 256) {
        float x = logits[v];
        float nm = fmaxf(m, x);
        l = l * expf(m - nm) + expf(x - nm);
        m = nm;
    }
    rm[tid] = m; rl[tid] = l; __syncthreads();
    for (int o = 128; o > 0; o >>= 1) {
        if (tid < o) {
            float m2 = rm[tid + o], l2 = rl[tid + o];
            float nm = fmaxf(rm[tid], m2);
            rl[tid] = rl[tid] * expf(rm[tid] - nm) + l2 * expf(m2 - nm);
            rm[tid] = nm;
        }
        __syncthreads();
    }
    if (tid == 0) { ms[blockIdx.x] = rm[0]; ls[blockIdx.x] = rl[0]; }
}

__global__ void k_sm2(const float* __restrict__ ms, const float* __restrict__ ls, float* __restrict__ g) {
    __shared__ float rm[128], rl[128];
    int tid = threadIdx.x;  // 128 threads
    rm[tid] = ms[tid]; rl[tid] = ls[tid]; __syncthreads();
    for (int o = 64; o > 0; o >>= 1) {
        if (tid < o) {
            float m2 = rm[tid + o], l2 = rl[tid + o];
            float nm = fmaxf(rm[tid], m2);
            rl[tid] = rl[tid] * expf(rm[tid] - nm) + l2 * expf(m2 - nm);
            rm[tid] = nm;
        }
        __syncthreads();
    }
    if (tid == 0) { g[0] = rm[0]; g[1] = 1.f / rl[0]; }
}

__global__ void k_sm3(const float* __restrict__ logits, const float* __restrict__ g,
                      float* __restrict__ out) {
    int v = blockIdx.x * 256 + threadIdx.x;
    if (v < VS) out[v] = expf(logits[v] - g[0]) * g[1];
}

extern "C" void kernel_launch(void* const* d_in, const int* in_sizes, int n_in,
                              void* d_out, int out_size, void* d_ws, size_t ws_size,
                              hipStream_t stream) {
    (void)in_sizes; (void)n_in; (void)out_size; (void)ws_size;
    const float* x          = (const float*)d_in[0];
    const float* enc        = (const float*)d_in[1];
    const int*   sentence   = (const int*)d_in[2];
    const float* prev_probs = (const float*)d_in[3];
    const float* h0         = (const float*)d_in[4];
    const float* c0         = (const float*)d_in[5];
    const float* attn_W     = (const float*)d_in[6];
    const float* attn_b     = (const float*)d_in[7];
    const float* comb_W     = (const float*)d_in[8];
    const float* comb_b     = (const float*)d_in[9];
    const float* Ws_W       = (const float*)d_in[10];
    const float* Ws_b       = (const float*)d_in[11];
    const float* Wo_W       = (const float*)d_in[12];
    const float* Wo_b       = (const float*)d_in[13];
    const float* Wc_W       = (const float*)d_in[14];
    const float* Wc_b       = (const float*)d_in[15];
    const float* W_ih       = (const float*)d_in[16];
    const float* W_hh       = (const float*)d_in[17];
    const float* b_ih       = (const float*)d_in[18];
    const float* b_hh       = (const float*)d_in[19];
    const int*   prev_word  = (const int*)d_in[20];
    float* ws  = (float*)d_ws;
    float* out = (float*)d_out;

    k_attn_logits<<<512, 256, 0, stream>>>(x, h0, attn_W, attn_b, ws + OFF_LOGA);
    k_prep<<<1, 256, 0, stream>>>(ws + OFF_LOGA, sentence, prev_probs, prev_word, x,
                                  ws + OFF_ATTW, ws + OFF_RHO, ws + OFF_LSTMIN, ws + OFF_CTX);
    k_ctx<<<dim3(2, 32), 256, 0, stream>>>(enc, ws + OFF_ATTW, ws + OFF_RHO,
                                           ws + OFF_CTX, ws + OFF_SEL);
    k_comb<<<512, 256, 0, stream>>>(ws + OFF_CTX, ws + OFF_SEL, comb_W, comb_b,
                                    Ws_W, Ws_b, ws + OFF_LSTMIN);
    k_gates_gemm<<<1280, 256, 0, stream>>>(ws + OFF_LSTMIN, h0, W_ih, W_hh, b_ih, b_hh,
                                           ws + OFF_GATES, enc, Wc_W,
                                           ws + OFF_T0, ws + OFF_T1);
    k_lstm<<<4, 256, 0, stream>>>(ws + OFF_GATES, c0, out, ws + OFF_H1);
    k_scores<<<13077, 256, 0, stream>>>(Wo_W, Wo_b, ws + OFF_T0, ws + OFF_T1, Wc_b,
                                        ws + OFF_H1, ws + OFF_LOG);
    k_sm1<<<128, 256, 0, stream>>>(ws + OFF_LOG, ws + OFF_MS, ws + OFF_LS);
    k_sm2<<<1, 128, 0, stream>>>(ws + OFF_MS, ws + OFF_LS, ws + OFF_G);
    k_sm3<<<205, 256, 0, stream>>>(ws + OFF_LOG, ws + OFF_G, out);
}